// Round 6
// baseline (937.904 us; speedup 1.0000x reference)
//
#include <hip/hip_runtime.h>

// out[b,d,t] = sum_c x[b,c,t] * weights[subjects[b],c,d]
// B=256, C=270, T=1024, NSUB=200. fp32 in/out, bf16 MFMA internally.
// Round-4 structure (depth-2 register prefetch + double-buffered LDS,
// 1 barrier/K-step) with a 3-bit 8B-slot XOR swizzle:
//   slot' = q ^ ((row>>4)&7)
// -> ds_write_b64 2-way (free), ds_read_b128 conflict-free.
// The XOR's odd bit swaps the two 8B k-halves of a 16B pair; swap parity
// (row>>4)&1 is uniform per fragment: B-frags iff n&1 (compile-time),
// A-frags iff (3*wr+m)&1 (wave-uniform branch -> compute_step<WR>).

#define C_    270
#define T_    1024
#define B_    256
#define NSUB_ 200

#define BM 96      // d-tile
#define BN 128     // t-tile
#define BK 32      // c-step
#define NK 9       // K padded 270 -> 288
#define ROWU32 20  // u32 per LDS row: 16 data + 4 pad (16B-aligned rows)
#define BOFF (BM * ROWU32)
#define LDSU32 ((BM + BN) * ROWU32)

typedef __attribute__((ext_vector_type(8))) short bf16x8;
typedef __attribute__((ext_vector_type(4))) float f32x4;
typedef __attribute__((ext_vector_type(2))) float f32x2;
typedef __attribute__((ext_vector_type(2))) unsigned u32x2;
typedef __attribute__((ext_vector_type(4))) int i32x4;

__device__ __forceinline__ unsigned pk(float lo, float hi) {
    // v_cvt_pk_bf16_f32: RNE, lo -> low 16 bits. No builtin on gfx950.
    unsigned r;
    asm("v_cvt_pk_bf16_f32 %0, %1, %2" : "=v"(r) : "v"(lo), "v"(hi));
    return r;
}

// Load one bf16x8 fragment from LDS (16B). SW: undo the k-half swap the
// odd slot-XOR bit introduced (pure register rename at compile time).
template<bool SW>
__device__ __forceinline__ bf16x8 ldfrag(const unsigned* p) {
    i32x4 u = *(const i32x4*)p;
    if (SW) { i32x4 v = {u[2], u[3], u[0], u[1]}; return __builtin_bit_cast(bf16x8, v); }
    return __builtin_bit_cast(bf16x8, u);
}

// A-tile at L, B-tile at L+BOFF. Frag addr: row*20 + 4*(lg ^ ((base>>5)&3)).
template<int WR>
__device__ __forceinline__ void compute_step(const unsigned* __restrict__ L,
                                             int wc, int lg, int lr,
                                             f32x4 (&acc)[3][4])
{
    const unsigned* __restrict__ LB = L + BOFF;
    bf16x8 af[3], bfr[4];
    // A frags: base = WR*48 + m*16 (compile-time); swap = ((base>>4)&1)
    af[0] = ldfrag<(((WR*48 +  0) >> 4) & 1) != 0>(L + (WR*48 +  0 + lr) * ROWU32 + 4 * (lg ^ (((WR*48 +  0) >> 5) & 3)));
    af[1] = ldfrag<(((WR*48 + 16) >> 4) & 1) != 0>(L + (WR*48 + 16 + lr) * ROWU32 + 4 * (lg ^ (((WR*48 + 16) >> 5) & 3)));
    af[2] = ldfrag<(((WR*48 + 32) >> 4) & 1) != 0>(L + (WR*48 + 32 + lr) * ROWU32 + 4 * (lg ^ (((WR*48 + 32) >> 5) & 3)));
    // B frags: base = wc*64 + n*16; swap = n&1 (compile-time); base>>5 runtime
    const int bb = wc * 64;
    bfr[0] = ldfrag<false>(LB + (bb +  0 + lr) * ROWU32 + 4 * (lg ^ (((bb +  0) >> 5) & 3)));
    bfr[1] = ldfrag<true >(LB + (bb + 16 + lr) * ROWU32 + 4 * (lg ^ (((bb + 16) >> 5) & 3)));
    bfr[2] = ldfrag<false>(LB + (bb + 32 + lr) * ROWU32 + 4 * (lg ^ (((bb + 32) >> 5) & 3)));
    bfr[3] = ldfrag<true >(LB + (bb + 48 + lr) * ROWU32 + 4 * (lg ^ (((bb + 48) >> 5) & 3)));
    #pragma unroll
    for (int m = 0; m < 3; ++m)
        #pragma unroll
        for (int n = 0; n < 4; ++n)
            acc[m][n] = __builtin_amdgcn_mfma_f32_16x16x32_bf16(af[m], bfr[n], acc[m][n], 0, 0, 0);
}

__global__ __launch_bounds__(256, 4)
void subj_layers_kernel(const float* __restrict__ x,
                        const int* __restrict__ subjects,
                        const float* __restrict__ w,
                        float* __restrict__ out)
{
    __shared__ unsigned lds[2][LDSU32];

    const int tid  = threadIdx.x;
    const int lane = tid & 63;
    const int wid  = tid >> 6;
    const int wr   = wid >> 1;   // wave d-row 0..1
    const int wc   = wid & 1;    // wave t-col 0..1
    const int lg   = lane >> 4;
    const int lr   = lane & 15;

    // Bijective XCD-chunk swizzle (6144 = 8 x 768), d-tile fastest.
    const int bid  = (blockIdx.x & 7) * 768 + (blockIdx.x >> 3);
    const int b    = bid / 24;
    const int rem  = bid % 24;
    const int d0   = (rem % 3) * BM;   // 0,96,192
    const int t0   = (rem / 3) * BN;   // 0..896

    int sub = subjects[b];
    sub = sub < 0 ? 0 : (sub >= NSUB_ ? NSUB_ - 1 : sub);
    const float* __restrict__ wsub = w + (size_t)sub * (C_ * C_);
    const float* __restrict__ xb   = x + (size_t)b * (C_ * T_);

    // ---- staging decomposition ----
    // B (x): thread = (t-quad btq, c-quad bcq): 4x float4 loads, 4x b64 writes
    const int btq = tid & 31;          // 0..31
    const int bcq = tid >> 5;          // 0..7
    const float* __restrict__ xbt = xb + (t0 + 4 * btq);
    const int colB = 2 * (bcq ^ ((btq >> 2) & 7));   // slot-XOR, const across j
    // A (w): 384 items (48 d-pairs x 8 c-quads), 1.5/thread
    const int adp0 = tid % 48,         acq0 = tid / 48;
    const int adp1 = (256 + tid) % 48, acq1 = (256 + tid) / 48;
    const bool hasA1 = (tid < 128);
    const int dA0 = d0 + 2 * adp0;  const bool dA0ok = (dA0 + 1 < C_);
    const int dA1 = d0 + 2 * adp1;  const bool dA1ok = (dA1 + 1 < C_);
    const int colA0 = 2 * (acq0 ^ ((adp0 >> 3) & 7));
    const int colA1 = 2 * (acq1 ^ ((adp1 >> 3) & 7));

    f32x4 acc[3][4];
    #pragma unroll
    for (int m = 0; m < 3; ++m)
        #pragma unroll
        for (int n = 0; n < 4; ++n)
            acc[m][n] = (f32x4){0.f, 0.f, 0.f, 0.f};

    auto load_tiles = [&](int c0, bool full, f32x4 pb[4], f32x2 pa0[4], f32x2 pa1[4]) {
        #pragma unroll
        for (int e = 0; e < 4; ++e) {
            const int c = c0 + 4 * bcq + e;
            pb[e] = (full || c < C_) ? *(const f32x4*)(xbt + (size_t)c * T_)
                                     : (f32x4){0.f, 0.f, 0.f, 0.f};
        }
        #pragma unroll
        for (int e = 0; e < 4; ++e) {
            const int c = c0 + 4 * acq0 + e;
            pa0[e] = (dA0ok && (full || c < C_)) ? *(const f32x2*)(wsub + (size_t)c * C_ + dA0)
                                                 : (f32x2){0.f, 0.f};
        }
        #pragma unroll
        for (int e = 0; e < 4; ++e) {
            const int c = c0 + 4 * acq1 + e;
            pa1[e] = (hasA1 && dA1ok && (full || c < C_)) ? *(const f32x2*)(wsub + (size_t)c * C_ + dA1)
                                                          : (f32x2){0.f, 0.f};
        }
    };

    auto store_tiles = [&](unsigned* L, const f32x4 pb[4], const f32x2 pa0[4], const f32x2 pa1[4]) {
        unsigned* LB = L + BOFF;
        #pragma unroll
        for (int j = 0; j < 4; ++j) {
            const int r = 4 * btq + j;
            u32x2 v;
            v.x = pk(pb[0][j], pb[1][j]);
            v.y = pk(pb[2][j], pb[3][j]);
            *(u32x2*)(LB + r * ROWU32 + colB) = v;
        }
        #pragma unroll
        for (int j = 0; j < 2; ++j) {
            const int r = 2 * adp0 + j;
            u32x2 v;
            v.x = pk(pa0[0][j], pa0[1][j]);
            v.y = pk(pa0[2][j], pa0[3][j]);
            *(u32x2*)(L + r * ROWU32 + colA0) = v;
        }
        if (hasA1) {
            #pragma unroll
            for (int j = 0; j < 2; ++j) {
                const int r = 2 * adp1 + j;
                u32x2 v;
                v.x = pk(pa1[0][j], pa1[1][j]);
                v.y = pk(pa1[2][j], pa1[3][j]);
                *(u32x2*)(L + r * ROWU32 + colA1) = v;
            }
        }
    };

    auto compute = [&](const unsigned* L) {
        if (wr == 0) compute_step<0>(L, wc, lg, lr, acc);
        else         compute_step<1>(L, wc, lg, lr, acc);
    };

    // ---- two named prefetch slots (static indexing) ----
    f32x4 pbA[4], pbB[4];
    f32x2 pa0A[4], pa1A[4], pa0B[4], pa1B[4];

    // prologue: tile0 -> lds0; tile1 in flight in slot B
    load_tiles(0, true, pbA, pa0A, pa1A);
    store_tiles(&lds[0][0], pbA, pa0A, pa1A);
    load_tiles(BK, true, pbB, pa0B, pa1B);
    __syncthreads();

    // main: tiles 0..5; loads t2..t7 all full
    #pragma unroll 1
    for (int kk = 0; kk < 6; kk += 2) {
        load_tiles((kk + 2) * BK, true, pbA, pa0A, pa1A);   // tile kk+2
        compute(&lds[0][0]);                                 // tile kk
        store_tiles(&lds[1][0], pbB, pa0B, pa1B);            // tile kk+1
        __syncthreads();
        load_tiles((kk + 3) * BK, true, pbB, pa0B, pa1B);   // tile kk+3
        compute(&lds[1][0]);                                 // tile kk+1
        store_tiles(&lds[0][0], pbA, pa0A, pa1A);            // tile kk+2
        __syncthreads();
    }
    // peeled tail: tiles 6,7,8 (tile 8 partial -> guarded load)
    load_tiles(8 * BK, false, pbA, pa0A, pa1A);
    compute(&lds[0][0]);                          // tile 6
    store_tiles(&lds[1][0], pbB, pa0B, pa1B);     // tile 7
    __syncthreads();
    compute(&lds[1][0]);                          // tile 7
    store_tiles(&lds[0][0], pbA, pa0A, pa1A);     // tile 8
    __syncthreads();
    compute(&lds[0][0]);                          // tile 8

    // ---- epilogue: C/D layout col=lane&15, row=(lane>>4)*4+reg ----
    float* outb = out + (size_t)b * (C_ * T_);
    #pragma unroll
    for (int m = 0; m < 3; ++m) {
        const int dbase = d0 + wr * 48 + m * 16 + 4 * lg;
        #pragma unroll
        for (int n = 0; n < 4; ++n) {
            const int t = t0 + wc * 64 + n * 16 + lr;
            #pragma unroll
            for (int rr = 0; rr < 4; ++rr) {
                const int d = dbase + rr;
                if (d < C_)
                    outb[(size_t)d * T_ + t] = acc[m][n][rr];
            }
        }
    }
}

extern "C" void kernel_launch(void* const* d_in, const int* in_sizes, int n_in,
                              void* d_out, int out_size, void* d_ws, size_t ws_size,
                              hipStream_t stream)
{
    const float* x        = (const float*)d_in[0];
    const int*   subjects = (const int*)d_in[1];
    const float* w        = (const float*)d_in[2];
    float* out            = (float*)d_out;

    dim3 grid(B_ * 24);  // 256 batches * (3 d-tiles * 8 t-tiles)
    dim3 block(256);
    hipLaunchKernelGGL(subj_layers_kernel, grid, block, 0, stream,
                       x, subjects, w, out);
}

// Round 7
// 533.049 us; speedup vs baseline: 1.7595x; 1.7595x over previous
//
#include <hip/hip_runtime.h>

// out[b,d,t] = sum_c x[b,c,t] * weights[subjects[b],c,d]
// B=256, C=270, T=1024, NSUB=200. fp32 in/out, bf16 MFMA internally.
// Depth-2 register prefetch + double-buffered LDS. One barrier per K-step,
// and the barrier waits ONLY lgkmcnt(0) (ds_writes) -- NOT vmcnt -- so the
// tile-(k+2) global loads stay in flight across it (T4 counted-wait idea).
// __launch_bounds__(256,3): (256,4) capped VGPR at 64 -> scratch spills
// (round-6: FETCH 183MB -> 1.37GB, 4.5x slower). 3-bit 8B-slot XOR swizzle
// on LDS (write 2-way = free, reads uniform); k-half swap parity is
// fragment-uniform and undone by a compile-time register rename.

#define C_    270
#define T_    1024
#define B_    256
#define NSUB_ 200

#define BM 96      // d-tile
#define BN 128     // t-tile
#define BK 32      // c-step
#define NK 9       // K padded 270 -> 288
#define ROWU32 20  // u32 per LDS row: 16 data + 4 pad (16B-aligned rows)
#define BOFF (BM * ROWU32)
#define LDSU32 ((BM + BN) * ROWU32)

typedef __attribute__((ext_vector_type(8))) short bf16x8;
typedef __attribute__((ext_vector_type(4))) float f32x4;
typedef __attribute__((ext_vector_type(2))) float f32x2;
typedef __attribute__((ext_vector_type(2))) unsigned u32x2;
typedef __attribute__((ext_vector_type(4))) int i32x4;

__device__ __forceinline__ unsigned pk(float lo, float hi) {
    // v_cvt_pk_bf16_f32: RNE, lo -> low 16 bits. No builtin on gfx950.
    unsigned r;
    asm("v_cvt_pk_bf16_f32 %0, %1, %2" : "=v"(r) : "v"(lo), "v"(hi));
    return r;
}

// Barrier that does NOT drain vmcnt: ds_writes must be visible (lgkmcnt(0))
// but in-flight global loads belong to future tiles -- keep them in flight.
// sched_barrier(0) fences pin ds ops on the correct side (rule #18).
__device__ __forceinline__ void tile_barrier() {
    __builtin_amdgcn_sched_barrier(0);
    asm volatile("s_waitcnt lgkmcnt(0)" ::: "memory");
    __builtin_amdgcn_s_barrier();
    __builtin_amdgcn_sched_barrier(0);
}

// Load one bf16x8 fragment from LDS (16B). SW: undo the k-half swap the
// odd slot-XOR bit introduced (pure register rename at compile time).
template<bool SW>
__device__ __forceinline__ bf16x8 ldfrag(const unsigned* p) {
    i32x4 u = *(const i32x4*)p;
    if (SW) { i32x4 v = {u[2], u[3], u[0], u[1]}; return __builtin_bit_cast(bf16x8, v); }
    return __builtin_bit_cast(bf16x8, u);
}

// A-tile at L, B-tile at L+BOFF. Frag addr: row*20 + 4*(lg ^ ((base>>5)&3)).
template<int WR>
__device__ __forceinline__ void compute_step(const unsigned* __restrict__ L,
                                             int wc, int lg, int lr,
                                             f32x4 (&acc)[3][4])
{
    const unsigned* __restrict__ LB = L + BOFF;
    bf16x8 af[3], bfr[4];
    af[0] = ldfrag<(((WR*48 +  0) >> 4) & 1) != 0>(L + (WR*48 +  0 + lr) * ROWU32 + 4 * (lg ^ (((WR*48 +  0) >> 5) & 3)));
    af[1] = ldfrag<(((WR*48 + 16) >> 4) & 1) != 0>(L + (WR*48 + 16 + lr) * ROWU32 + 4 * (lg ^ (((WR*48 + 16) >> 5) & 3)));
    af[2] = ldfrag<(((WR*48 + 32) >> 4) & 1) != 0>(L + (WR*48 + 32 + lr) * ROWU32 + 4 * (lg ^ (((WR*48 + 32) >> 5) & 3)));
    const int bb = wc * 64;
    bfr[0] = ldfrag<false>(LB + (bb +  0 + lr) * ROWU32 + 4 * (lg ^ (((bb +  0) >> 5) & 3)));
    bfr[1] = ldfrag<true >(LB + (bb + 16 + lr) * ROWU32 + 4 * (lg ^ (((bb + 16) >> 5) & 3)));
    bfr[2] = ldfrag<false>(LB + (bb + 32 + lr) * ROWU32 + 4 * (lg ^ (((bb + 32) >> 5) & 3)));
    bfr[3] = ldfrag<true >(LB + (bb + 48 + lr) * ROWU32 + 4 * (lg ^ (((bb + 48) >> 5) & 3)));
    #pragma unroll
    for (int m = 0; m < 3; ++m)
        #pragma unroll
        for (int n = 0; n < 4; ++n)
            acc[m][n] = __builtin_amdgcn_mfma_f32_16x16x32_bf16(af[m], bfr[n], acc[m][n], 0, 0, 0);
}

__global__ __launch_bounds__(256, 3)
void subj_layers_kernel(const float* __restrict__ x,
                        const int* __restrict__ subjects,
                        const float* __restrict__ w,
                        float* __restrict__ out)
{
    __shared__ unsigned lds[2][LDSU32];

    const int tid  = threadIdx.x;
    const int lane = tid & 63;
    const int wid  = tid >> 6;
    const int wr   = wid >> 1;   // wave d-row 0..1
    const int wc   = wid & 1;    // wave t-col 0..1
    const int lg   = lane >> 4;
    const int lr   = lane & 15;

    // Bijective XCD-chunk swizzle (6144 = 8 x 768), d-tile fastest.
    const int bid  = (blockIdx.x & 7) * 768 + (blockIdx.x >> 3);
    const int b    = bid / 24;
    const int rem  = bid % 24;
    const int d0   = (rem % 3) * BM;   // 0,96,192
    const int t0   = (rem / 3) * BN;   // 0..896

    int sub = subjects[b];
    sub = sub < 0 ? 0 : (sub >= NSUB_ ? NSUB_ - 1 : sub);
    const float* __restrict__ wsub = w + (size_t)sub * (C_ * C_);
    const float* __restrict__ xb   = x + (size_t)b * (C_ * T_);

    // ---- staging decomposition ----
    // B (x): thread = (t-quad btq, c-quad bcq): 4x float4 loads, 4x b64 writes
    const int btq = tid & 31;          // 0..31
    const int bcq = tid >> 5;          // 0..7
    const float* __restrict__ xbt = xb + (t0 + 4 * btq);
    const int colB = 2 * (bcq ^ ((btq >> 2) & 7));   // slot-XOR, const across j
    // A (w): 384 items (48 d-pairs x 8 c-quads), 1.5/thread
    const int adp0 = tid % 48,         acq0 = tid / 48;
    const int adp1 = (256 + tid) % 48, acq1 = (256 + tid) / 48;
    const bool hasA1 = (tid < 128);
    const int dA0 = d0 + 2 * adp0;  const bool dA0ok = (dA0 + 1 < C_);
    const int dA1 = d0 + 2 * adp1;  const bool dA1ok = (dA1 + 1 < C_);
    const int colA0 = 2 * (acq0 ^ ((adp0 >> 3) & 7));
    const int colA1 = 2 * (acq1 ^ ((adp1 >> 3) & 7));

    f32x4 acc[3][4];
    #pragma unroll
    for (int m = 0; m < 3; ++m)
        #pragma unroll
        for (int n = 0; n < 4; ++n)
            acc[m][n] = (f32x4){0.f, 0.f, 0.f, 0.f};

    auto load_tiles = [&](int c0, bool full, f32x4 pb[4], f32x2 pa0[4], f32x2 pa1[4]) {
        #pragma unroll
        for (int e = 0; e < 4; ++e) {
            const int c = c0 + 4 * bcq + e;
            pb[e] = (full || c < C_) ? *(const f32x4*)(xbt + (size_t)c * T_)
                                     : (f32x4){0.f, 0.f, 0.f, 0.f};
        }
        #pragma unroll
        for (int e = 0; e < 4; ++e) {
            const int c = c0 + 4 * acq0 + e;
            pa0[e] = (dA0ok && (full || c < C_)) ? *(const f32x2*)(wsub + (size_t)c * C_ + dA0)
                                                 : (f32x2){0.f, 0.f};
        }
        #pragma unroll
        for (int e = 0; e < 4; ++e) {
            const int c = c0 + 4 * acq1 + e;
            pa1[e] = (hasA1 && dA1ok && (full || c < C_)) ? *(const f32x2*)(wsub + (size_t)c * C_ + dA1)
                                                          : (f32x2){0.f, 0.f};
        }
    };

    auto store_tiles = [&](unsigned* L, const f32x4 pb[4], const f32x2 pa0[4], const f32x2 pa1[4]) {
        unsigned* LB = L + BOFF;
        #pragma unroll
        for (int j = 0; j < 4; ++j) {
            const int r = 4 * btq + j;
            u32x2 v;
            v.x = pk(pb[0][j], pb[1][j]);
            v.y = pk(pb[2][j], pb[3][j]);
            *(u32x2*)(LB + r * ROWU32 + colB) = v;
        }
        #pragma unroll
        for (int j = 0; j < 2; ++j) {
            const int r = 2 * adp0 + j;
            u32x2 v;
            v.x = pk(pa0[0][j], pa0[1][j]);
            v.y = pk(pa0[2][j], pa0[3][j]);
            *(u32x2*)(L + r * ROWU32 + colA0) = v;
        }
        if (hasA1) {
            #pragma unroll
            for (int j = 0; j < 2; ++j) {
                const int r = 2 * adp1 + j;
                u32x2 v;
                v.x = pk(pa1[0][j], pa1[1][j]);
                v.y = pk(pa1[2][j], pa1[3][j]);
                *(u32x2*)(L + r * ROWU32 + colA1) = v;
            }
        }
    };

    auto compute = [&](const unsigned* L) {
        if (wr == 0) compute_step<0>(L, wc, lg, lr, acc);
        else         compute_step<1>(L, wc, lg, lr, acc);
    };

    // ---- two named prefetch slots (static indexing) ----
    f32x4 pbA[4], pbB[4];
    f32x2 pa0A[4], pa1A[4], pa0B[4], pa1B[4];

    // prologue: tile0 -> lds0; tile1 in flight in slot B
    load_tiles(0, true, pbA, pa0A, pa1A);
    store_tiles(&lds[0][0], pbA, pa0A, pa1A);
    load_tiles(BK, true, pbB, pa0B, pa1B);
    tile_barrier();

    // main: tiles 0..5; loads t2..t7 all full. Loads for tile k+2 are issued
    // before compute(k) and SURVIVE the phase barrier (lgkm-only).
    #pragma unroll 1
    for (int kk = 0; kk < 6; kk += 2) {
        load_tiles((kk + 2) * BK, true, pbA, pa0A, pa1A);   // tile kk+2
        compute(&lds[0][0]);                                 // tile kk
        store_tiles(&lds[1][0], pbB, pa0B, pa1B);            // tile kk+1
        tile_barrier();
        load_tiles((kk + 3) * BK, true, pbB, pa0B, pa1B);   // tile kk+3
        compute(&lds[1][0]);                                 // tile kk+1
        store_tiles(&lds[0][0], pbA, pa0A, pa1A);            // tile kk+2
        tile_barrier();
    }
    // peeled tail: tiles 6,7,8 (tile 8 partial -> guarded load)
    load_tiles(8 * BK, false, pbA, pa0A, pa1A);
    compute(&lds[0][0]);                          // tile 6
    store_tiles(&lds[1][0], pbB, pa0B, pa1B);     // tile 7
    tile_barrier();
    compute(&lds[1][0]);                          // tile 7
    store_tiles(&lds[0][0], pbA, pa0A, pa1A);     // tile 8
    tile_barrier();
    compute(&lds[0][0]);                          // tile 8

    // ---- epilogue: C/D layout col=lane&15, row=(lane>>4)*4+reg ----
    float* outb = out + (size_t)b * (C_ * T_);
    #pragma unroll
    for (int m = 0; m < 3; ++m) {
        const int dbase = d0 + wr * 48 + m * 16 + 4 * lg;
        #pragma unroll
        for (int n = 0; n < 4; ++n) {
            const int t = t0 + wc * 64 + n * 16 + lr;
            #pragma unroll
            for (int rr = 0; rr < 4; ++rr) {
                const int d = dbase + rr;
                if (d < C_)
                    outb[(size_t)d * T_ + t] = acc[m][n][rr];
            }
        }
    }
}

extern "C" void kernel_launch(void* const* d_in, const int* in_sizes, int n_in,
                              void* d_out, int out_size, void* d_ws, size_t ws_size,
                              hipStream_t stream)
{
    const float* x        = (const float*)d_in[0];
    const int*   subjects = (const int*)d_in[1];
    const float* w        = (const float*)d_in[2];
    float* out            = (float*)d_out;

    dim3 grid(B_ * 24);  // 256 batches * (3 d-tiles * 8 t-tiles)
    dim3 block(256);
    hipLaunchKernelGGL(subj_layers_kernel, grid, block, 0, stream,
                       x, subjects, w, out);
}

// Round 8
// 203.740 us; speedup vs baseline: 4.6034x; 2.6163x over previous
//
#include <hip/hip_runtime.h>

// out[b,d,t] = sum_c x[b,c,t] * weights[subjects[b],c,d]
// B=256, C=270, T=1024, NSUB=200. fp32 in/out, bf16 MFMA internally.
// 64(d) x 128(t) tile, 4 waves (2x2), wave-tile 32x64, acc 2x4 frags.
// Single-slot register prefetch ordered {compute k; store k+1; load k+2;
// lgkm-only barrier} -> load survives the barrier (no vmcnt drain, NO
// sched_barrier fences - R7 showed fences force spills). Live set ~100
// VGPR so the allocator keeps the schedule without sinking or spilling.
// 3-bit 8B-slot XOR LDS swizzle (R4-proven); k-half swap parity is m&1 /
// n&1, undone by compile-time register rename in ldfrag<SW>.

#define C_    270
#define T_    1024
#define B_    256
#define NSUB_ 200

#define BM 64      // d-tile
#define BN 128     // t-tile
#define BK 32      // c-step
#define NK 9       // K padded 270 -> 288
#define ROWU32 20  // u32 per LDS row: 16 data + 4 pad (16B-aligned rows)
#define BOFF (BM * ROWU32)
#define LDSU32 ((BM + BN) * ROWU32)   // 3840 u32 = 15,360 B per buffer

typedef __attribute__((ext_vector_type(8))) short bf16x8;
typedef __attribute__((ext_vector_type(4))) float f32x4;
typedef __attribute__((ext_vector_type(2))) float f32x2;
typedef __attribute__((ext_vector_type(2))) unsigned u32x2;
typedef __attribute__((ext_vector_type(4))) int i32x4;

__device__ __forceinline__ unsigned pk(float lo, float hi) {
    // v_cvt_pk_bf16_f32: RNE, lo -> low 16 bits. No builtin on gfx950.
    unsigned r;
    asm("v_cvt_pk_bf16_f32 %0, %1, %2" : "=v"(r) : "v"(lo), "v"(hi));
    return r;
}

// Barrier draining ONLY lgkmcnt (ds_writes visible to the workgroup).
// Global loads in flight target registers for future tiles -- keep them.
__device__ __forceinline__ void tile_barrier() {
    asm volatile("s_waitcnt lgkmcnt(0)" ::: "memory");
    __builtin_amdgcn_s_barrier();
}

// Load one bf16x8 fragment (16B). SW: undo the k-half swap the odd
// slot-XOR bit introduced (compile-time register rename).
template<bool SW>
__device__ __forceinline__ bf16x8 ldfrag(const unsigned* p) {
    i32x4 u = *(const i32x4*)p;
    if (SW) { i32x4 v = {u[2], u[3], u[0], u[1]}; return __builtin_bit_cast(bf16x8, v); }
    return __builtin_bit_cast(bf16x8, u);
}

__global__ __launch_bounds__(256, 3)
void subj_layers_kernel(const float* __restrict__ x,
                        const int* __restrict__ subjects,
                        const float* __restrict__ w,
                        float* __restrict__ out)
{
    __shared__ unsigned lds[2][LDSU32];

    const int tid  = threadIdx.x;
    const int lane = tid & 63;
    const int wid  = tid >> 6;
    const int wr   = wid >> 1;   // wave d-row 0..1 (32 rows each)
    const int wc   = wid & 1;    // wave t-col 0..1 (64 cols each)
    const int lg   = lane >> 4;
    const int lr   = lane & 15;

    // Bijective XCD-chunk swizzle (10240 = 8 x 1280), d-tile fastest so the
    // 5 d-blocks sharing one x-slice are same-XCD and temporally adjacent.
    const int bid  = (blockIdx.x & 7) * 1280 + (blockIdx.x >> 3);
    const int b    = bid / 40;
    const int rem  = bid % 40;
    const int d0   = (rem % 5) * BM;   // 0,64,128,192,256
    const int t0   = (rem / 5) * BN;   // 0..896

    int sub = subjects[b];
    sub = sub < 0 ? 0 : (sub >= NSUB_ ? NSUB_ - 1 : sub);
    const float* __restrict__ wsub = w + (size_t)sub * (C_ * C_);
    const float* __restrict__ xb   = x + (size_t)b * (C_ * T_);

    // ---- staging decomposition (1 item/thread each) ----
    // B (x): thread = (t-quad btq 0..31, c-quad bcq 0..7): 4x float4 loads.
    const int btq = tid & 31;
    const int bcq = tid >> 5;
    const float* __restrict__ xbt = xb + (t0 + 4 * btq);
    const int colB = 2 * (bcq ^ ((btq >> 2) & 7));
    // A (w): thread = (d-pair adp 0..31, c-quad acq 0..7): 4x f32x2 loads.
    const int adp = tid & 31;
    const int acq = tid >> 5;
    const int dA  = d0 + 2 * adp;
    const bool dAok = (dA + 1 < C_);
    const int colA = 2 * (acq ^ ((adp >> 3) & 7));

    f32x4 acc[2][4];
    #pragma unroll
    for (int m = 0; m < 2; ++m)
        #pragma unroll
        for (int n = 0; n < 4; ++n)
            acc[m][n] = (f32x4){0.f, 0.f, 0.f, 0.f};

    // single prefetch slot
    f32x4 pb[4];
    f32x2 pa[4];

    auto load_tiles = [&](int c0, bool full) {
        #pragma unroll
        for (int e = 0; e < 4; ++e) {
            const int c = c0 + 4 * bcq + e;
            pb[e] = (full || c < C_) ? *(const f32x4*)(xbt + (size_t)c * T_)
                                     : (f32x4){0.f, 0.f, 0.f, 0.f};
        }
        #pragma unroll
        for (int e = 0; e < 4; ++e) {
            const int c = c0 + 4 * acq + e;
            pa[e] = (dAok && (full || c < C_)) ? *(const f32x2*)(wsub + (size_t)c * C_ + dA)
                                               : (f32x2){0.f, 0.f};
        }
    };

    auto store_tiles = [&](unsigned* L) {
        unsigned* LB = L + BOFF;
        #pragma unroll
        for (int j = 0; j < 4; ++j) {
            const int r = 4 * btq + j;
            u32x2 v;
            v.x = pk(pb[0][j], pb[1][j]);
            v.y = pk(pb[2][j], pb[3][j]);
            *(u32x2*)(LB + r * ROWU32 + colB) = v;
        }
        #pragma unroll
        for (int j = 0; j < 2; ++j) {
            const int r = 2 * adp + j;
            u32x2 v;
            v.x = pk(pa[0][j], pa[1][j]);
            v.y = pk(pa[2][j], pa[3][j]);
            *(u32x2*)(L + r * ROWU32 + colA) = v;
        }
    };

    auto compute = [&](const unsigned* L) {
        const unsigned* LB = L + BOFF;
        bf16x8 af[2], bfr[4];
        // A frags: base = wr*32 + 16m; swap = m&1; chunk XOR = lg ^ wr.
        const int ab = wr * 32;
        af[0] = ldfrag<false>(L + (ab +  0 + lr) * ROWU32 + 4 * (lg ^ wr));
        af[1] = ldfrag<true >(L + (ab + 16 + lr) * ROWU32 + 4 * (lg ^ wr));
        // B frags: base = wc*64 + 16n; swap = n&1; chunk XOR = lg ^ ((base>>5)&3).
        const int bb = wc * 64;
        bfr[0] = ldfrag<false>(LB + (bb +  0 + lr) * ROWU32 + 4 * (lg ^ (((bb +  0) >> 5) & 3)));
        bfr[1] = ldfrag<true >(LB + (bb + 16 + lr) * ROWU32 + 4 * (lg ^ (((bb + 16) >> 5) & 3)));
        bfr[2] = ldfrag<false>(LB + (bb + 32 + lr) * ROWU32 + 4 * (lg ^ (((bb + 32) >> 5) & 3)));
        bfr[3] = ldfrag<true >(LB + (bb + 48 + lr) * ROWU32 + 4 * (lg ^ (((bb + 48) >> 5) & 3)));
        #pragma unroll
        for (int m = 0; m < 2; ++m)
            #pragma unroll
            for (int n = 0; n < 4; ++n)
                acc[m][n] = __builtin_amdgcn_mfma_f32_16x16x32_bf16(af[m], bfr[n], acc[m][n], 0, 0, 0);
    };

    // ---- pipeline: slot holds tile k+1 at iter-k entry ----
    load_tiles(0, true);
    store_tiles(&lds[0][0]);
    load_tiles(BK, true);
    tile_barrier();

    #pragma unroll 1
    for (int k = 0; k < 6; ++k) {
        compute(&lds[k & 1][0]);              // tile k
        store_tiles(&lds[(k + 1) & 1][0]);    // tile k+1 (slot)
        load_tiles((k + 2) * BK, true);       // tile k+2 -> crosses barrier
        tile_barrier();
    }
    // k=6: prefetch of tile 8 is c-guarded
    compute(&lds[0][0]);                      // tile 6
    store_tiles(&lds[1][0]);                  // tile 7
    load_tiles(8 * BK, false);                // tile 8 (partial)
    tile_barrier();
    // k=7
    compute(&lds[1][0]);                      // tile 7
    store_tiles(&lds[0][0]);                  // tile 8
    tile_barrier();
    compute(&lds[0][0]);                      // tile 8

    // ---- epilogue: C/D layout col=lane&15, row=(lane>>4)*4+reg ----
    float* outb = out + (size_t)b * (C_ * T_);
    #pragma unroll
    for (int m = 0; m < 2; ++m) {
        const int dbase = d0 + wr * 32 + m * 16 + 4 * lg;
        #pragma unroll
        for (int n = 0; n < 4; ++n) {
            const int t = t0 + wc * 64 + n * 16 + lr;
            #pragma unroll
            for (int rr = 0; rr < 4; ++rr) {
                const int d = dbase + rr;
                if (d < C_)
                    outb[(size_t)d * T_ + t] = acc[m][n][rr];
            }
        }
    }
}

extern "C" void kernel_launch(void* const* d_in, const int* in_sizes, int n_in,
                              void* d_out, int out_size, void* d_ws, size_t ws_size,
                              hipStream_t stream)
{
    const float* x        = (const float*)d_in[0];
    const int*   subjects = (const int*)d_in[1];
    const float* w        = (const float*)d_in[2];
    float* out            = (float*)d_out;

    dim3 grid(B_ * 40);  // 256 batches * (5 d-tiles * 8 t-tiles) = 10240
    dim3 block(256);
    hipLaunchKernelGGL(subj_layers_kernel, grid, block, 0, stream,
                       x, subjects, w, out);
}